// Round 1
// baseline (837.862 us; speedup 1.0000x reference)
//
#include <hip/hip_runtime.h>

#define HD 1024
#define NS 64
#define NB 8
#define LS 2048
#define MT (NB*LS)        // 16384 rows
#define N2 128            // 2*NS
#define CHL 32            // scan chunk length
#define NCH (LS/CHL)      // 64 chunks

// workspace offsets (floats)
#define OFF_BUR 0
#define OFF_BUI (MT*NS)                 // 1,048,576
#define OFF_S   (2*MT*NS)               // 2,097,152
#define OFF_FR  (OFF_S + MT*N2)         // 4,194,304
#define OFF_FI  (OFF_FR + NB*NS*NCH)
#define OFF_CR  (OFF_FI + NB*NS*NCH)
#define OFF_CI  (OFF_CR + NB*NS*NCH)
#define OFF_E2  (OFF_CI + NB*NS*NCH)
// end = OFF_E2 + 128*1024 = 4,456,448 floats = 17.8 MB

__device__ __forceinline__ void lbar_of(int n, const float* __restrict__ logLr,
                                        const float* __restrict__ Li, float dt,
                                        float& ar, float& ai) {
    float lr  = -expf(logLr[n]);
    float mag = expf(lr * dt);
    float ang = Li[n] * dt;
    ar = mag * cosf(ang);
    ai = mag * sinf(ang);
}

// ---------------- kernel 1: Bu projection -----------------------------------
// Bu_r/Bu_i (MT x 64) = x (MT x 1024) @ (dt*B)^T.  64-row x 128-col tile/block.
__global__ __launch_bounds__(256) void k_proj(const float* __restrict__ x,
                                              const float* __restrict__ Br,
                                              const float* __restrict__ Bi,
                                              const float* __restrict__ log_dt,
                                              float* __restrict__ bur,
                                              float* __restrict__ bui) {
    __shared__ float Xs[32][64 + 4];    // [kk][row]
    __shared__ float Bs[32][128 + 4];   // [kk][n2]
    const float dt = expf(log_dt[0]);
    const int m0 = blockIdx.x * 64;
    const int tid = threadIdx.x;
    const int ty = tid >> 4, tx = tid & 15;   // ty: 4 rows each, tx: 8 cols each
    float acc[4][8] = {};
    for (int kt = 0; kt < 1024; kt += 32) {
        #pragma unroll
        for (int i = 0; i < 2; ++i) {
            int e = tid + i * 256, row = e >> 3, kq = e & 7;
            float4 v = *(const float4*)&x[(size_t)(m0 + row) * HD + kt + kq * 4];
            Xs[kq*4+0][row] = v.x; Xs[kq*4+1][row] = v.y;
            Xs[kq*4+2][row] = v.z; Xs[kq*4+3][row] = v.w;
        }
        #pragma unroll
        for (int i = 0; i < 4; ++i) {
            int e = tid + i * 256, n2 = e >> 3, kq = e & 7;
            const float* src = (n2 < NS) ? &Br[(size_t)n2 * HD + kt + kq * 4]
                                         : &Bi[(size_t)(n2 - NS) * HD + kt + kq * 4];
            float4 v = *(const float4*)src;
            Bs[kq*4+0][n2] = v.x * dt; Bs[kq*4+1][n2] = v.y * dt;
            Bs[kq*4+2][n2] = v.z * dt; Bs[kq*4+3][n2] = v.w * dt;
        }
        __syncthreads();
        #pragma unroll
        for (int kk = 0; kk < 32; ++kk) {
            float a[4], b[8];
            *(float4*)&a[0] = *(float4*)&Xs[kk][ty * 4];
            *(float4*)&b[0] = *(float4*)&Bs[kk][tx * 8];
            *(float4*)&b[4] = *(float4*)&Bs[kk][tx * 8 + 4];
            #pragma unroll
            for (int r = 0; r < 4; ++r)
                #pragma unroll
                for (int c = 0; c < 8; ++c) acc[r][c] += a[r] * b[c];
        }
        __syncthreads();
    }
    #pragma unroll
    for (int r = 0; r < 4; ++r) {
        int m = m0 + ty * 4 + r;
        float4 v0 = {acc[r][0], acc[r][1], acc[r][2], acc[r][3]};
        float4 v1 = {acc[r][4], acc[r][5], acc[r][6], acc[r][7]};
        if (tx < 8) {
            *(float4*)&bur[(size_t)m * NS + tx * 8]     = v0;
            *(float4*)&bur[(size_t)m * NS + tx * 8 + 4] = v1;
        } else {
            *(float4*)&bui[(size_t)m * NS + (tx - 8) * 8]     = v0;
            *(float4*)&bui[(size_t)m * NS + (tx - 8) * 8 + 4] = v1;
        }
    }
}

// ---------------- kernel 2: scan phase 1 (local chunk scans) ----------------
__global__ __launch_bounds__(256) void k_scan1(const float* __restrict__ bur,
                                               const float* __restrict__ bui,
                                               const float* __restrict__ logLr,
                                               const float* __restrict__ Li,
                                               const float* __restrict__ log_dt,
                                               float* __restrict__ S,
                                               float* __restrict__ Fr,
                                               float* __restrict__ Fi) {
    int g = blockIdx.x * 256 + threadIdx.x;       // 32768 = 8b * 64ch * 64n
    int n = g & 63, ch = (g >> 6) & 63, b = g >> 12;
    float dt = expf(log_dt[0]);
    float ar, ai; lbar_of(n, logLr, Li, dt, ar, ai);
    float sr = 0.f, si = 0.f;
    size_t base = (size_t)b * LS + ch * CHL;
    for (int j = 0; j < CHL; ++j) {
        size_t m = base + j;
        float ur = bur[m * NS + n], ui = bui[m * NS + n];
        float nr = ar * sr - ai * si + ur;
        float ni = ar * si + ai * sr + ui;
        sr = nr; si = ni;
        S[m * N2 + n]      = sr;
        S[m * N2 + NS + n] = si;
    }
    int fi = (b * NS + n) * NCH + ch;
    Fr[fi] = sr; Fi[fi] = si;
}

// ---------------- kernel 3: scan phase 2 (carry scan + final states) --------
__global__ __launch_bounds__(256) void k_scan2(const float* __restrict__ Fr,
                                               const float* __restrict__ Fi,
                                               const float* __restrict__ logLr,
                                               const float* __restrict__ Li,
                                               const float* __restrict__ log_dt,
                                               float* __restrict__ CexR,
                                               float* __restrict__ CexI,
                                               float* __restrict__ out_tail) {
    int g = blockIdx.x * 256 + threadIdx.x;       // 512 = 8b * 64n
    if (g >= NB * NS) return;
    int n = g & 63;
    float dt = expf(log_dt[0]);
    float ar, ai; lbar_of(n, logLr, Li, dt, ar, ai);
    float Ar = ar, Ai = ai;                        // a^32 via 5 squarings
    #pragma unroll
    for (int s = 0; s < 5; ++s) { float nr = Ar*Ar - Ai*Ai; Ai = 2.f*Ar*Ai; Ar = nr; }
    float cr = 0.f, ci = 0.f;
    for (int ch = 0; ch < NCH; ++ch) {
        CexR[g * NCH + ch] = cr; CexI[g * NCH + ch] = ci;
        float fr = Fr[g * NCH + ch], fi2 = Fi[g * NCH + ch];
        float nr = Ar * cr - Ai * ci + fr;
        float ni = Ar * ci + Ai * cr + fi2;
        cr = nr; ci = ni;
    }
    out_tail[g]          = cr;    // sr final (B,N)
    out_tail[NB*NS + g]  = ci;    // si final
}

// ---------------- kernel 4: scan phase 3 (fixup) ----------------------------
__global__ __launch_bounds__(256) void k_fix(const float* __restrict__ CexR,
                                             const float* __restrict__ CexI,
                                             const float* __restrict__ logLr,
                                             const float* __restrict__ Li,
                                             const float* __restrict__ log_dt,
                                             float* __restrict__ S) {
    int g = blockIdx.x * 256 + threadIdx.x;
    int n = g & 63, ch = (g >> 6) & 63, b = g >> 12;
    float cr = CexR[(b * NS + n) * NCH + ch];
    float ci = CexI[(b * NS + n) * NCH + ch];
    if (cr == 0.f && ci == 0.f) return;           // chunk 0 (and exact zeros)
    float dt = expf(log_dt[0]);
    float ar, ai; lbar_of(n, logLr, Li, dt, ar, ai);
    float pr = ar, pi = ai;                        // a^(j+1)
    size_t base = (size_t)b * LS + ch * CHL;
    for (int j = 0; j < CHL; ++j) {
        size_t m = base + j;
        S[m * N2 + n]      += pr * cr - pi * ci;
        S[m * N2 + NS + n] += pr * ci + pi * cr;
        float nr = pr * ar - pi * ai; pi = pr * ai + pi * ar; pr = nr;
    }
}

// ---------------- kernel 5: E2 = [C_r^T; -C_i^T] @ W^T  (128 x 1024) --------
__global__ __launch_bounds__(256) void k_e2(const float* __restrict__ W,
                                            const float* __restrict__ Cr,
                                            const float* __restrict__ Ci,
                                            float* __restrict__ E2) {
    __shared__ float Ws[16][33];        // [hh][kk]
    __shared__ float Cs[32][128 + 4];   // [kk][n2]
    const int h0 = blockIdx.x * 16;
    const int tid = threadIdx.x;
    const int hh = tid & 15, ng = tid >> 4;       // thread: 1 h x 8 n2
    float acc[8] = {};
    for (int kt = 0; kt < 1024; kt += 32) {
        { int e = tid;        Ws[e >> 5][e & 31] = W[(size_t)(h0 + (e >> 5)) * HD + kt + (e & 31)]; }
        { int e = tid + 256;  Ws[e >> 5][e & 31] = W[(size_t)(h0 + (e >> 5)) * HD + kt + (e & 31)]; }
        #pragma unroll
        for (int i = 0; i < 16; ++i) {
            int e = tid + i * 256, kk = e >> 7, n2 = e & 127;
            Cs[kk][n2] = (n2 < NS) ? Cr[(size_t)(kt + kk) * NS + n2]
                                   : Ci[(size_t)(kt + kk) * NS + n2 - NS];
        }
        __syncthreads();
        #pragma unroll
        for (int kk = 0; kk < 32; ++kk) {
            float w = Ws[hh][kk];
            #pragma unroll
            for (int j = 0; j < 8; ++j) acc[j] += w * Cs[kk][ng * 8 + j];
        }
        __syncthreads();
    }
    #pragma unroll
    for (int j = 0; j < 8; ++j) {
        int n2 = ng * 8 + j;
        E2[(size_t)n2 * HD + h0 + hh] = (n2 >= NS) ? -acc[j] : acc[j];
    }
}

// ---------------- kernel 6: main GEMM ---------------------------------------
// out[m,h] = sum_k x[m,k]*D[k]*W[h,k] + sum_n2 S[m,n2]*E2[n2,h] + b[h]
__global__ __launch_bounds__(256) void k_gemm(const float* __restrict__ x,
                                              const float* __restrict__ S,
                                              const float* __restrict__ W,
                                              const float* __restrict__ E2,
                                              const float* __restrict__ Dv,
                                              const float* __restrict__ bo,
                                              float* __restrict__ out) {
    __shared__ float As[32][128 + 4];   // [kk][row]
    __shared__ float Bs[32][128 + 4];   // [kk][h]
    const int m0 = blockIdx.x * 128, h0 = blockIdx.y * 128;
    const int tid = threadIdx.x;
    const int ty = tid >> 4, tx = tid & 15;       // 8x8 per thread
    float acc[8][8] = {};
    for (int kt = 0; kt < 1152; kt += 32) {
        if (kt < 1024) {
            #pragma unroll
            for (int i = 0; i < 4; ++i) {
                int e = tid + i * 256, row = e >> 3, kq = e & 7;
                float4 v = *(const float4*)&x[(size_t)(m0 + row) * HD + kt + kq * 4];
                As[kq*4+0][row] = v.x; As[kq*4+1][row] = v.y;
                As[kq*4+2][row] = v.z; As[kq*4+3][row] = v.w;
            }
            #pragma unroll
            for (int i = 0; i < 4; ++i) {
                int e = tid + i * 256, hh = e >> 3, kq = e & 7;
                float4 v = *(const float4*)&W[(size_t)(h0 + hh) * HD + kt + kq * 4];
                float4 d = *(const float4*)&Dv[kt + kq * 4];
                Bs[kq*4+0][hh] = v.x * d.x; Bs[kq*4+1][hh] = v.y * d.y;
                Bs[kq*4+2][hh] = v.z * d.z; Bs[kq*4+3][hh] = v.w * d.w;
            }
        } else {
            const int n2off = kt - 1024;
            #pragma unroll
            for (int i = 0; i < 4; ++i) {
                int e = tid + i * 256, row = e >> 3, kq = e & 7;
                float4 v = *(const float4*)&S[(size_t)(m0 + row) * N2 + n2off + kq * 4];
                As[kq*4+0][row] = v.x; As[kq*4+1][row] = v.y;
                As[kq*4+2][row] = v.z; As[kq*4+3][row] = v.w;
            }
            #pragma unroll
            for (int i = 0; i < 4; ++i) {
                int e = tid + i * 256, kk = e >> 5, hq = e & 31;
                float4 v = *(const float4*)&E2[(size_t)(n2off + kk) * HD + h0 + hq * 4];
                Bs[kk][hq*4+0] = v.x; Bs[kk][hq*4+1] = v.y;
                Bs[kk][hq*4+2] = v.z; Bs[kk][hq*4+3] = v.w;
            }
        }
        __syncthreads();
        #pragma unroll
        for (int kk = 0; kk < 32; ++kk) {
            float a[8], b[8];
            *(float4*)&a[0] = *(float4*)&As[kk][ty * 8];
            *(float4*)&a[4] = *(float4*)&As[kk][ty * 8 + 4];
            *(float4*)&b[0] = *(float4*)&Bs[kk][tx * 8];
            *(float4*)&b[4] = *(float4*)&Bs[kk][tx * 8 + 4];
            #pragma unroll
            for (int r = 0; r < 8; ++r)
                #pragma unroll
                for (int c = 0; c < 8; ++c) acc[r][c] += a[r] * b[c];
        }
        __syncthreads();
    }
    #pragma unroll
    for (int r = 0; r < 8; ++r) {
        int m = m0 + ty * 8 + r, h = h0 + tx * 8;
        float4 b0 = *(const float4*)&bo[h];
        float4 b1 = *(const float4*)&bo[h + 4];
        float4 v0 = {acc[r][0]+b0.x, acc[r][1]+b0.y, acc[r][2]+b0.z, acc[r][3]+b0.w};
        float4 v1 = {acc[r][4]+b1.x, acc[r][5]+b1.y, acc[r][6]+b1.z, acc[r][7]+b1.w};
        *(float4*)&out[(size_t)m * HD + h]     = v0;
        *(float4*)&out[(size_t)m * HD + h + 4] = v1;
    }
}

extern "C" void kernel_launch(void* const* d_in, const int* in_sizes, int n_in,
                              void* d_out, int out_size, void* d_ws, size_t ws_size,
                              hipStream_t stream) {
    const float* x      = (const float*)d_in[0];
    const float* logLr  = (const float*)d_in[1];
    const float* Li     = (const float*)d_in[2];
    const float* Br     = (const float*)d_in[3];
    const float* Bi     = (const float*)d_in[4];
    const float* Cr     = (const float*)d_in[5];
    const float* Ci     = (const float*)d_in[6];
    const float* Dv     = (const float*)d_in[7];
    const float* log_dt = (const float*)d_in[8];
    const float* W      = (const float*)d_in[9];
    const float* bo     = (const float*)d_in[10];
    float* out = (float*)d_out;
    float* ws  = (float*)d_ws;

    float* bur  = ws + OFF_BUR;
    float* bui  = ws + OFF_BUI;
    float* S    = ws + OFF_S;
    float* Fr   = ws + OFF_FR;
    float* Fi   = ws + OFF_FI;
    float* CexR = ws + OFF_CR;
    float* CexI = ws + OFF_CI;
    float* E2   = ws + OFF_E2;

    k_proj <<<MT / 64, 256, 0, stream>>>(x, Br, Bi, log_dt, bur, bui);
    k_e2   <<<HD / 16, 256, 0, stream>>>(W, Cr, Ci, E2);
    k_scan1<<<(NB * NS * NCH) / 256, 256, 0, stream>>>(bur, bui, logLr, Li, log_dt, S, Fr, Fi);
    k_scan2<<<2, 256, 0, stream>>>(Fr, Fi, logLr, Li, log_dt, CexR, CexI, out + (size_t)MT * HD);
    k_fix  <<<(NB * NS * NCH) / 256, 256, 0, stream>>>(CexR, CexI, logLr, Li, log_dt, S);
    k_gemm <<<dim3(MT / 128, HD / 128), 256, 0, stream>>>(x, S, W, E2, Dv, bo, out);
}

// Round 2
// 289.342 us; speedup vs baseline: 2.8958x; 2.8958x over previous
//
#include <hip/hip_runtime.h>

#define HD 1024
#define NS 64
#define NB 8
#define LS 2048
#define MT (NB*LS)        // 16384 rows
#define N2 128            // 2*NS
#define KA 1152           // HD + N2, A/B leading dim (K-extended)
#define CHL 32            // scan chunk length
#define NCH (LS/CHL)      // 64 chunks

typedef __attribute__((ext_vector_type(8))) short short8;
typedef __attribute__((ext_vector_type(4))) float f32x4;

// ---- workspace byte offsets -------------------------------------------------
#define OB_ABUF 0u                               // bf16 [16384][1152]  37,748,736
#define OB_BMAT (OB_ABUF + MT*KA*2)              // bf16 [1024][1152]    2,359,296
#define OB_BMP  (OB_BMAT + HD*KA*2)              // bf16 [128][1024]       262,144
#define OB_BU   (OB_BMP  + N2*HD*2)              // f32  [16384][128]    8,388,608
#define OB_FR   (OB_BU   + MT*N2*4)              // f32  [8*64*64]         131,072
#define OB_FI   (OB_FR   + NB*NS*NCH*4)
#define OB_CR   (OB_FI   + NB*NS*NCH*4)
#define OB_CI   (OB_CR   + NB*NS*NCH*4)
// end ~ 49.3 MB

__device__ __forceinline__ unsigned short f2bf(float f) {
    unsigned u = __float_as_uint(f);
    u = (u + 0x7FFFu + ((u >> 16) & 1u)) >> 16;
    return (unsigned short)u;
}

__device__ __forceinline__ void lbar_of(int n, const float* __restrict__ logLr,
                                        const float* __restrict__ Li, float dt,
                                        float& ar, float& ai) {
    float lr  = -expf(logLr[n]);
    float mag = expf(lr * dt);
    float ang = Li[n] * dt;
    ar = mag * cosf(ang);
    ai = mag * sinf(ang);
}

// ---------------- cast x -> Abuf cols 0..1023 (bf16) ------------------------
__global__ __launch_bounds__(256) void k_cast_x(const float* __restrict__ x,
                                                unsigned short* __restrict__ Ab) {
    size_t idx = ((size_t)blockIdx.x * 256 + threadIdx.x) * 8;
    int m = (int)(idx >> 10), k = (int)(idx & 1023);
    float4 v0 = *(const float4*)&x[idx];
    float4 v1 = *(const float4*)&x[idx + 4];
    short8 s;
    s[0]=f2bf(v0.x); s[1]=f2bf(v0.y); s[2]=f2bf(v0.z); s[3]=f2bf(v0.w);
    s[4]=f2bf(v1.x); s[5]=f2bf(v1.y); s[6]=f2bf(v1.z); s[7]=f2bf(v1.w);
    *(short8*)&Ab[(size_t)m * KA + k] = s;
}

// ---------------- Bmat cols 0..1023 = bf16(D[k]*W[h,k]) ---------------------
__global__ __launch_bounds__(256) void k_prep_w(const float* __restrict__ W,
                                                const float* __restrict__ Dv,
                                                unsigned short* __restrict__ Bm) {
    size_t idx = ((size_t)blockIdx.x * 256 + threadIdx.x) * 8;
    int h = (int)(idx >> 10), k = (int)(idx & 1023);
    float4 v0 = *(const float4*)&W[idx];
    float4 v1 = *(const float4*)&W[idx + 4];
    float4 d0 = *(const float4*)&Dv[k];
    float4 d1 = *(const float4*)&Dv[k + 4];
    short8 s;
    s[0]=f2bf(v0.x*d0.x); s[1]=f2bf(v0.y*d0.y); s[2]=f2bf(v0.z*d0.z); s[3]=f2bf(v0.w*d0.w);
    s[4]=f2bf(v1.x*d1.x); s[5]=f2bf(v1.y*d1.y); s[6]=f2bf(v1.z*d1.z); s[7]=f2bf(v1.w*d1.w);
    *(short8*)&Bm[(size_t)h * KA + k] = s;
}

// ---------------- BmatP [n2][k] = bf16(dt * (Br|Bi)) ------------------------
__global__ __launch_bounds__(256) void k_prep_bp(const float* __restrict__ Br,
                                                 const float* __restrict__ Bi,
                                                 const float* __restrict__ log_dt,
                                                 unsigned short* __restrict__ Bp) {
    size_t idx = ((size_t)blockIdx.x * 256 + threadIdx.x) * 8;
    int n2 = (int)(idx >> 10), k = (int)(idx & 1023);
    float dt = expf(log_dt[0]);
    const float* src = (n2 < NS) ? &Br[(size_t)n2 * HD + k] : &Bi[(size_t)(n2 - NS) * HD + k];
    float4 v0 = *(const float4*)&src[0];
    float4 v1 = *(const float4*)&src[4];
    short8 s;
    s[0]=f2bf(v0.x*dt); s[1]=f2bf(v0.y*dt); s[2]=f2bf(v0.z*dt); s[3]=f2bf(v0.w*dt);
    s[4]=f2bf(v1.x*dt); s[5]=f2bf(v1.y*dt); s[6]=f2bf(v1.z*dt); s[7]=f2bf(v1.w*dt);
    *(short8*)&Bp[(size_t)n2 * HD + k] = s;
}

// ---------------- E2T[h][n2] = sum_k W[h,k]*(Cr|-Ci)[k][n2] -> Bmat cols 1024+
__global__ __launch_bounds__(256) void k_e2(const float* __restrict__ W,
                                            const float* __restrict__ Cr,
                                            const float* __restrict__ Ci,
                                            unsigned short* __restrict__ Bm) {
    __shared__ float Ws[16][33];        // [hh][kk]
    __shared__ float Cs[32][128 + 4];   // [kk][n2]
    const int h0 = blockIdx.x * 16;
    const int tid = threadIdx.x;
    const int hh = tid & 15, ng = tid >> 4;       // thread: 1 h x 8 n2
    float acc[8] = {};
    for (int kt = 0; kt < 1024; kt += 32) {
        { int e = tid;        Ws[e >> 5][e & 31] = W[(size_t)(h0 + (e >> 5)) * HD + kt + (e & 31)]; }
        { int e = tid + 256;  Ws[e >> 5][e & 31] = W[(size_t)(h0 + (e >> 5)) * HD + kt + (e & 31)]; }
        #pragma unroll
        for (int i = 0; i < 16; ++i) {
            int e = tid + i * 256, kk = e >> 7, n2 = e & 127;
            Cs[kk][n2] = (n2 < NS) ? Cr[(size_t)(kt + kk) * NS + n2]
                                   : Ci[(size_t)(kt + kk) * NS + n2 - NS];
        }
        __syncthreads();
        #pragma unroll
        for (int kk = 0; kk < 32; ++kk) {
            float w = Ws[hh][kk];
            #pragma unroll
            for (int j = 0; j < 8; ++j) acc[j] += w * Cs[kk][ng * 8 + j];
        }
        __syncthreads();
    }
    #pragma unroll
    for (int j = 0; j < 8; ++j) {
        int n2 = ng * 8 + j;
        Bm[(size_t)(h0 + hh) * KA + HD + n2] = f2bf((n2 >= NS) ? -acc[j] : acc[j]);
    }
}

// ---------------- scan pass A: per-chunk carry-out (from zero state) --------
__global__ __launch_bounds__(256) void k_carry(const float* __restrict__ Bu,
                                               const float* __restrict__ logLr,
                                               const float* __restrict__ Li,
                                               const float* __restrict__ log_dt,
                                               float* __restrict__ Fr,
                                               float* __restrict__ Fi) {
    int g = blockIdx.x * 256 + threadIdx.x;       // 32768 = 8b * 64ch * 64n
    int n = g & 63, ch = (g >> 6) & 63, b = g >> 12;
    float dt = expf(log_dt[0]);
    float ar, ai; lbar_of(n, logLr, Li, dt, ar, ai);
    float sr = 0.f, si = 0.f;
    size_t base = ((size_t)b * LS + ch * CHL) * N2;
    for (int j = 0; j < CHL; ++j) {
        float ur = Bu[base + j * N2 + n];
        float ui = Bu[base + j * N2 + NS + n];
        float nr = ar * sr - ai * si + ur;
        float ni = ar * si + ai * sr + ui;
        sr = nr; si = ni;
    }
    int fi = (b * NS + n) * NCH + ch;
    Fr[fi] = sr; Fi[fi] = si;
}

// ---------------- scan pass B: carry scan + final states --------------------
__global__ __launch_bounds__(256) void k_scan2(const float* __restrict__ Fr,
                                               const float* __restrict__ Fi,
                                               const float* __restrict__ logLr,
                                               const float* __restrict__ Li,
                                               const float* __restrict__ log_dt,
                                               float* __restrict__ CexR,
                                               float* __restrict__ CexI,
                                               float* __restrict__ out_tail) {
    int g = blockIdx.x * 256 + threadIdx.x;       // 512 = 8b * 64n
    if (g >= NB * NS) return;
    int n = g & 63;
    float dt = expf(log_dt[0]);
    float ar, ai; lbar_of(n, logLr, Li, dt, ar, ai);
    float Ar = ar, Ai = ai;                        // a^32 via 5 squarings
    #pragma unroll
    for (int s = 0; s < 5; ++s) { float nr = Ar*Ar - Ai*Ai; Ai = 2.f*Ar*Ai; Ar = nr; }
    float cr = 0.f, ci = 0.f;
    for (int ch = 0; ch < NCH; ++ch) {
        CexR[g * NCH + ch] = cr; CexI[g * NCH + ch] = ci;
        float fr = Fr[g * NCH + ch], fi2 = Fi[g * NCH + ch];
        float nr = Ar * cr - Ai * ci + fr;
        float ni = Ar * ci + Ai * cr + fi2;
        cr = nr; ci = ni;
    }
    out_tail[g]          = cr;    // sr final (B,N)
    out_tail[NB*NS + g]  = ci;    // si final
}

// ---------------- scan pass C: replay with carry, write bf16 S into Abuf ----
__global__ __launch_bounds__(256) void k_scan3(const float* __restrict__ Bu,
                                               const float* __restrict__ CexR,
                                               const float* __restrict__ CexI,
                                               const float* __restrict__ logLr,
                                               const float* __restrict__ Li,
                                               const float* __restrict__ log_dt,
                                               unsigned short* __restrict__ Ab) {
    int g = blockIdx.x * 256 + threadIdx.x;
    int n = g & 63, ch = (g >> 6) & 63, b = g >> 12;
    float dt = expf(log_dt[0]);
    float ar, ai; lbar_of(n, logLr, Li, dt, ar, ai);
    int ci_idx = (b * NS + n) * NCH + ch;
    float sr = CexR[ci_idx], si = CexI[ci_idx];
    size_t base = ((size_t)b * LS + ch * CHL);
    for (int j = 0; j < CHL; ++j) {
        size_t m = base + j;
        float ur = Bu[(m) * N2 + n];
        float ui = Bu[(m) * N2 + NS + n];
        float nr = ar * sr - ai * si + ur;
        float ni = ar * si + ai * sr + ui;
        sr = nr; si = ni;
        Ab[m * KA + HD + n]      = f2bf(sr);
        Ab[m * KA + HD + NS + n] = f2bf(si);
    }
}

// ---------------- MFMA GEMM: out[M,N] = A[M,K] * B[N,K]^T (+bias) -----------
// m97 structure: 128x128 tile, BK=32, 4 waves (2x2), global_load_lds w=16.
template<int KTOT, int LDB, int LDO, bool BIAS>
__global__ __launch_bounds__(256) void k_mfma_gemm(const unsigned short* __restrict__ A,
                                                   int lda,
                                                   const unsigned short* __restrict__ B,
                                                   const float* __restrict__ bias,
                                                   float* __restrict__ out) {
    __shared__ unsigned short At[128 * 32];
    __shared__ unsigned short Bt[128 * 32];
    const int m0 = blockIdx.x * 128, n0 = blockIdx.y * 128;
    const int tid = threadIdx.x, wv = tid >> 6, ln = tid & 63;
    const int wr = wv >> 1, wc = wv & 1;
    const int r16 = ln & 15, kg = ln >> 4;
    f32x4 zero = {0.f, 0.f, 0.f, 0.f};
    f32x4 acc[4][4];
    #pragma unroll
    for (int i = 0; i < 4; ++i)
        #pragma unroll
        for (int j = 0; j < 4; ++j) acc[i][j] = zero;

    for (int kt = 0; kt < KTOT; kt += 32) {
        #pragma unroll
        for (int i = 0; i < 2; ++i) {
            int e = i * 4096 + wv * 1024 + ln * 16;   // byte offset within 8KB tile
            int row = e >> 6, kb = e & 63;
            const char* ga = (const char*)A + ((size_t)(m0 + row) * lda + kt) * 2 + kb;
            __builtin_amdgcn_global_load_lds(
                (const __attribute__((address_space(1))) void*)ga,
                (__attribute__((address_space(3))) void*)((char*)At + i * 4096 + wv * 1024),
                16, 0, 0);
            const char* gb = (const char*)B + ((size_t)(n0 + row) * LDB + kt) * 2 + kb;
            __builtin_amdgcn_global_load_lds(
                (const __attribute__((address_space(1))) void*)gb,
                (__attribute__((address_space(3))) void*)((char*)Bt + i * 4096 + wv * 1024),
                16, 0, 0);
        }
        __syncthreads();
        short8 af[4], bf[4];
        #pragma unroll
        for (int i = 0; i < 4; ++i) {
            af[i] = *(const short8*)&At[(wr * 64 + i * 16 + r16) * 32 + kg * 8];
            bf[i] = *(const short8*)&Bt[(wc * 64 + i * 16 + r16) * 32 + kg * 8];
        }
        #pragma unroll
        for (int i = 0; i < 4; ++i)
            #pragma unroll
            for (int j = 0; j < 4; ++j)
                acc[i][j] = __builtin_amdgcn_mfma_f32_16x16x32_bf16(af[i], bf[j], acc[i][j], 0, 0, 0);
        __syncthreads();
    }
    // epilogue: C/D layout col=lane&15, row=(lane>>4)*4+reg  [m89/m91]
    #pragma unroll
    for (int j = 0; j < 4; ++j) {
        int col = n0 + wc * 64 + j * 16 + r16;
        float bv = BIAS ? bias[col] : 0.f;
        #pragma unroll
        for (int i = 0; i < 4; ++i) {
            #pragma unroll
            for (int r = 0; r < 4; ++r) {
                int row = m0 + wr * 64 + i * 16 + kg * 4 + r;
                out[(size_t)row * LDO + col] = acc[i][j][r] + bv;
            }
        }
    }
}

extern "C" void kernel_launch(void* const* d_in, const int* in_sizes, int n_in,
                              void* d_out, int out_size, void* d_ws, size_t ws_size,
                              hipStream_t stream) {
    const float* x      = (const float*)d_in[0];
    const float* logLr  = (const float*)d_in[1];
    const float* Li     = (const float*)d_in[2];
    const float* Br     = (const float*)d_in[3];
    const float* Bi     = (const float*)d_in[4];
    const float* Cr     = (const float*)d_in[5];
    const float* Ci     = (const float*)d_in[6];
    const float* Dv     = (const float*)d_in[7];
    const float* log_dt = (const float*)d_in[8];
    const float* W      = (const float*)d_in[9];
    const float* bo     = (const float*)d_in[10];
    float* out = (float*)d_out;
    char*  ws  = (char*)d_ws;

    unsigned short* Abuf = (unsigned short*)(ws + OB_ABUF);
    unsigned short* Bmat = (unsigned short*)(ws + OB_BMAT);
    unsigned short* Bmp  = (unsigned short*)(ws + OB_BMP);
    float* Bu   = (float*)(ws + OB_BU);
    float* Fr   = (float*)(ws + OB_FR);
    float* Fi   = (float*)(ws + OB_FI);
    float* CexR = (float*)(ws + OB_CR);
    float* CexI = (float*)(ws + OB_CI);

    k_cast_x <<<MT * HD / 2048, 256, 0, stream>>>(x, Abuf);
    k_prep_w <<<HD * HD / 2048, 256, 0, stream>>>(W, Dv, Bmat);
    k_prep_bp<<<N2 * HD / 2048, 256, 0, stream>>>(Br, Bi, log_dt, Bmp);
    k_e2     <<<HD / 16, 256, 0, stream>>>(W, Cr, Ci, Bmat);
    // Bu = x_bf16 @ BmatP^T   (M=16384, N=128, K=1024)
    k_mfma_gemm<1024, 1024, 128, false><<<dim3(MT / 128, 1), 256, 0, stream>>>(Abuf, KA, Bmp, nullptr, Bu);
    k_carry  <<<(NB * NS * NCH) / 256, 256, 0, stream>>>(Bu, logLr, Li, log_dt, Fr, Fi);
    k_scan2  <<<2, 256, 0, stream>>>(Fr, Fi, logLr, Li, log_dt, CexR, CexI, out + (size_t)MT * HD);
    k_scan3  <<<(NB * NS * NCH) / 256, 256, 0, stream>>>(Bu, CexR, CexI, logLr, Li, log_dt, Abuf);
    // out = Abuf @ Bmat^T + bias   (M=16384, N=1024, K=1152)
    k_mfma_gemm<KA, KA, HD, true><<<dim3(MT / 128, HD / 128), 256, 0, stream>>>(Abuf, KA, Bmat, bo, out);
}